// Round 5
// baseline (294.376 us; speedup 1.0000x reference)
//
#include <hip/hip_runtime.h>
#include <math.h>

#define NEG_SLOPE 0.2f

using f16   = _Float16;
using f16x4 = __attribute__((ext_vector_type(4))) _Float16;
using f16x8 = __attribute__((ext_vector_type(8))) _Float16;
using f32x4 = __attribute__((ext_vector_type(4))) float;

// ---------------- CSR build ----------------

__global__ void count_dst(const int* __restrict__ dst, int* __restrict__ counts, int E) {
    int e = blockIdx.x * blockDim.x + threadIdx.x;
    if (e < E) atomicAdd(&counts[dst[e]], 1);
}

__global__ void scan_local(const int* __restrict__ counts, int* __restrict__ indptr,
                           int* __restrict__ blocksums, int n) {
    __shared__ int sdata[256];
    int b = blockIdx.x, t = threadIdx.x;
    int base = b * 1024 + t * 4;
    int v[4];
    int sum = 0;
#pragma unroll
    for (int j = 0; j < 4; j++) {
        int idx = base + j;
        v[j] = (idx < n) ? counts[idx] : 0;
        sum += v[j];
    }
    sdata[t] = sum;
    __syncthreads();
    for (int o = 1; o < 256; o <<= 1) {
        int u = 0;
        if (t >= o) u = sdata[t - o];
        __syncthreads();
        if (t >= o) sdata[t] += u;
        __syncthreads();
    }
    int excl = (t > 0) ? sdata[t - 1] : 0;
    int run = excl;
#pragma unroll
    for (int j = 0; j < 4; j++) {
        int idx = base + j;
        if (idx < n) indptr[idx] = run;
        run += v[j];
    }
    if (t == 255) blocksums[b] = sdata[255];
}

__global__ void scan_carry(int* __restrict__ blocksums, int nb) {
    int t = threadIdx.x;
    int v = (t < nb) ? blocksums[t] : 0;
    int orig = v;
#pragma unroll
    for (int o = 1; o < 64; o <<= 1) {
        int u = __shfl_up(v, o);
        if (t >= o) v += u;
    }
    if (t < nb) blocksums[t] = v - orig;
}

__global__ void scan_add(int* __restrict__ indptr, const int* __restrict__ blocksums,
                         int n, int Etot) {
    int b = blockIdx.x, t = threadIdx.x;
    int base = b * 1024 + t * 4;
    int add = blocksums[b];
#pragma unroll
    for (int j = 0; j < 4; j++) {
        int idx = base + j;
        if (idx < n) indptr[idx] += add;
    }
    if (b == 0 && t == 0) indptr[n] = Etot;
}

__global__ void fill_csr(const int* __restrict__ dst, const int* __restrict__ src,
                         int* __restrict__ cursor, int* __restrict__ csrc,
                         int* __restrict__ cdst, int E) {
    int e = blockIdx.x * blockDim.x + threadIdx.x;
    if (e < E) {
        int d = dst[e];
        int p = atomicAdd(&cursor[d], 1);
        csrc[p] = src[e];
        cdst[p] = d;
    }
}

// ---------------- f16-MFMA GEMM: C[M][BN] = A[M][256] * B[BN][256]^T, C in f16 ----

template <int BN, typename TA>
__global__ __launch_bounds__(256) void gemm_mfma(const TA* __restrict__ A,
                                                 const float* __restrict__ B,
                                                 f16* __restrict__ C, int M) {
    constexpr int K = 256;
    constexpr int WAVES_N = BN / 64;
    constexpr int WAVES_M = 4 / WAVES_N;
    constexpr int WM = 64 / WAVES_M;
    constexpr int MF = WM / 16;

    __shared__ f16 as[64][40];
    __shared__ f16 bs[BN][40];

    int t = threadIdx.x;
    int wave = t >> 6, lane = t & 63;
    int wn = wave / WAVES_M;
    int wm = wave % WAVES_M;
    int row0 = blockIdx.x * 64;

    int srow = t >> 2;
    int skq = (t & 3) * 8;

    int lrow = lane & 15;
    int ksel = (lane >> 4) * 8;

    f32x4 acc[MF][4] = {};

    for (int k0 = 0; k0 < K; k0 += 32) {
        {
            int gr = row0 + srow;
            gr = gr < M ? gr : M - 1;
            if constexpr (sizeof(TA) == 4) {
                const float4* pa = (const float4*)(A + (size_t)gr * K + k0 + skq);
                float4 u0 = pa[0], u1 = pa[1];
                f16x8 av;
                av[0] = (f16)u0.x; av[1] = (f16)u0.y; av[2] = (f16)u0.z; av[3] = (f16)u0.w;
                av[4] = (f16)u1.x; av[5] = (f16)u1.y; av[6] = (f16)u1.z; av[7] = (f16)u1.w;
                *(f16x8*)&as[srow][skq] = av;
            } else {
                *(f16x8*)&as[srow][skq] = *(const f16x8*)(A + (size_t)gr * K + k0 + skq);
            }
        }
#pragma unroll
        for (int i = 0; i < BN / 64; i++) {
            int n = i * 64 + srow;
            const float4* pb = (const float4*)(B + (size_t)n * K + k0 + skq);
            float4 u0 = pb[0], u1 = pb[1];
            f16x8 bv;
            bv[0] = (f16)u0.x; bv[1] = (f16)u0.y; bv[2] = (f16)u0.z; bv[3] = (f16)u0.w;
            bv[4] = (f16)u1.x; bv[5] = (f16)u1.y; bv[6] = (f16)u1.z; bv[7] = (f16)u1.w;
            *(f16x8*)&bs[n][skq] = bv;
        }
        __syncthreads();

        f16x8 af[MF], bf[4];
#pragma unroll
        for (int i = 0; i < MF; i++)
            af[i] = *(const f16x8*)&as[wm * WM + i * 16 + lrow][ksel];
#pragma unroll
        for (int j = 0; j < 4; j++)
            bf[j] = *(const f16x8*)&bs[wn * 64 + j * 16 + lrow][ksel];
#pragma unroll
        for (int i = 0; i < MF; i++)
#pragma unroll
            for (int j = 0; j < 4; j++)
                acc[i][j] = __builtin_amdgcn_mfma_f32_16x16x32_f16(af[i], bf[j], acc[i][j], 0, 0, 0);
        __syncthreads();
    }

#pragma unroll
    for (int i = 0; i < MF; i++) {
        int r0 = row0 + wm * WM + i * 16 + (lane >> 4) * 4;
#pragma unroll
        for (int j = 0; j < 4; j++) {
            int col = wn * 64 + j * 16 + (lane & 15);
#pragma unroll
            for (int r = 0; r < 4; r++) {
                int gr = r0 + r;
                if (gr < M) C[(size_t)gr * BN + col] = (f16)acc[i][j][r];
            }
        }
    }
}

// ---------------- attention scalars: el/er per node per head ----------------

template <int HEADS>
__global__ __launch_bounds__(256) void elr_kernel(const f16* __restrict__ h,
                                                  const float* __restrict__ al,
                                                  const float* __restrict__ ar,
                                                  float* __restrict__ el,
                                                  float* __restrict__ er, int N) {
    constexpr int F = HEADS * 64;
    constexpr int LPN = HEADS * 16;
    constexpr int NPW = 64 / LPN;
    int t = threadIdx.x;
    int wave = t >> 6, lane = t & 63;
    int node = (blockIdx.x * 4 + wave) * NPW + lane / LPN;
    int fl = lane % LPN;
    int feat = fl * 4;
    int head = feat >> 6;
    if (node >= N) return;
    f16x4 hv = *(const f16x4*)&h[(size_t)node * F + feat];
    float4 av = *(const float4*)&al[feat];
    float4 rv = *(const float4*)&ar[feat];
    float a_ = (float)hv[0] * av.x + (float)hv[1] * av.y + (float)hv[2] * av.z + (float)hv[3] * av.w;
    float b_ = (float)hv[0] * rv.x + (float)hv[1] * rv.y + (float)hv[2] * rv.z + (float)hv[3] * rv.w;
#pragma unroll
    for (int o = 1; o <= 8; o <<= 1) {
        a_ += __shfl_xor(a_, o);
        b_ += __shfl_xor(b_, o);
    }
    if ((lane & 15) == 0) {
        el[node * HEADS + head] = a_;
        er[node * HEADS + head] = b_;
    }
}

// ---------------- per-node softmax max & inv-sum precompute ----------------
// wave per node; lane = e*HEADS + h.

template <int HEADS>
__global__ __launch_bounds__(256) void ms_kernel(const float* __restrict__ el,
                                                 const float* __restrict__ er,
                                                 const int* __restrict__ indptr,
                                                 const int* __restrict__ csrc,
                                                 float* __restrict__ m_out,
                                                 float* __restrict__ invs_out, int N) {
    constexpr int EPC = 64 / HEADS;
    int wv = threadIdx.x >> 6, lane = threadIdx.x & 63;
    int node = blockIdx.x * 4 + wv;
    if (node >= N) return;
    int beg = indptr[node], end = indptr[node + 1], deg = end - beg;
    if (deg == 0) return;
    int h = lane % HEADS;
    int e = lane / HEADS;
    float erh = er[node * HEADS + h];
    float m = -INFINITY, s = 0.f;
    for (int c0 = 0; c0 < deg; c0 += EPC) {
        int i = c0 + e;
        float lg = -INFINITY;
        if (i < deg) {
            int sd = csrc[beg + i];
            lg = el[sd * HEADS + h] + erh;
            lg = lg >= 0.f ? lg : NEG_SLOPE * lg;
        }
        float cm = lg;
#pragma unroll
        for (int o = HEADS; o < 64; o <<= 1) cm = fmaxf(cm, __shfl_xor(cm, o));
        float mnew = fmaxf(m, cm);
        float p = (i < deg) ? __expf(lg - mnew) : 0.f;
#pragma unroll
        for (int o = HEADS; o < 64; o <<= 1) p += __shfl_xor(p, o);
        float r = (m > -INFINITY) ? __expf(m - mnew) : 0.f;
        s = s * r + p;
        m = mnew;
    }
    if (e == 0) {
        m_out[node * HEADS + h] = m;
        invs_out[node * HEADS + h] = 1.f / s;
    }
}

// ---------------- MFMA segment aggregation ----------------
// Block = 16 consecutive dst nodes. Per 32-edge K-step:
//  C[16n][D] += A[16n][32e] x H[32e][D],  A[n][e] = alpha (owner-masked).
// H staged in LDS as [blk=head*4+ft][ (e>>2)*64 + (e&3)*16 + dd ] (f16 elems);
// B-frag loaded via ds_read_b64_tr_b16 (per-lane addr = base + lane*8):
//  lane l gets elems (l&15) + j*16 + (l>>4)*64  ->  H[e=4*(l>>4)+j][d=l&15];
// K-permutation sigma(kb,j): j<4 -> 4*kb+j ; j>=4 -> 16+4*kb+(j-4). A uses same sigma.

template <int HEADS, bool RELU, typename TOUT>
__global__ __launch_bounds__(256) void agg_mfma(
        const f16* __restrict__ h, const float* __restrict__ el,
        const float* __restrict__ er, const float* __restrict__ m_,
        const float* __restrict__ invs, const float* __restrict__ bias,
        const int* __restrict__ indptr, const int* __restrict__ csrc,
        const int* __restrict__ cdst, TOUT* __restrict__ out, int N, int E) {
    constexpr int F = HEADS * 64;
    constexpr int TPW = (HEADS == 4) ? 4 : 1;   // N-tiles per wave
    constexpr int FPT = F / 8;                  // feats per staging thread

    __shared__ f16 lh[HEADS * 4 * 512];
    __shared__ unsigned int af[32 * HEADS];

    int t = threadIdx.x;
    int wv = t >> 6, lane = t & 63;
    int n0 = blockIdx.x * 16;
    int ntop = (n0 + 16 < N) ? n0 + 16 : N;
    int kbeg = indptr[n0], kend = indptr[ntop];
    int head = (HEADS == 4) ? wv : 0;

    f32x4 acc[TPW];
#pragma unroll
    for (int i = 0; i < TPW; i++) acc[i] = (f32x4){0.f, 0.f, 0.f, 0.f};

    int n_ = lane & 15, kb = lane >> 4;

    for (int kb0 = kbeg; kb0 < kend; kb0 += 32) {
        __syncthreads();
        // ---- stage H tile: 32 edges x F feats, vectorized writes ----
        {
            int e = t >> 3;
            int pos = kb0 + e;
            int posc = pos < E ? pos : E - 1;
            int gs = csrc[posc];
            const f16* row = h + (size_t)gs * F;
            int ebase = (e >> 2) * 64 + (e & 3) * 16;
#pragma unroll
            for (int i = 0; i < FPT / 8; i++) {
                int f = (t & 7) * FPT + i * 8;
                f16x8 v = *(const f16x8*)(row + f);
                *(f16x8*)&lh[(f >> 4) * 512 + ebase + (f & 15)] = v;
            }
        }
        // ---- per-edge alpha (packed owner<<16 | f16 bits) ----
        if (t < 32 * HEADS) {
            int e = t / HEADS, hh = t % HEADS;
            int pos = kb0 + e;
            unsigned int pack = 0;
            if (pos < kend) {
                int sd = csrc[pos];
                int dn = cdst[pos];
                float lg = el[sd * HEADS + hh] + er[dn * HEADS + hh];
                lg = lg >= 0.f ? lg : NEG_SLOPE * lg;
                float a = __expf(lg - m_[dn * HEADS + hh]) * invs[dn * HEADS + hh];
                f16 a16 = (f16)a;
                unsigned short ab = __builtin_bit_cast(unsigned short, a16);
                pack = ((unsigned int)(dn - n0) << 16) | (unsigned int)ab;
            }
            af[e * HEADS + hh] = pack;
        }
        __syncthreads();

        // ---- A fragment: alpha[sigma(kb,j)] masked by owner==n_ ----
        union { unsigned int u[4]; f16x8 v; } afr;
#pragma unroll
        for (int jj = 0; jj < 8; jj++) {
            int e = (jj < 4) ? (kb * 4 + jj) : (16 + kb * 4 + (jj - 4));
            unsigned int v = af[e * HEADS + head];
            unsigned int ab = ((v >> 16) == (unsigned int)n_) ? (v & 0xffffu) : 0u;
            if (jj & 1) afr.u[jj >> 1] |= ab << 16;
            else        afr.u[jj >> 1] = ab;
        }

        // ---- B fragments via hardware transpose read ----
        f16x4 b0[TPW], b1[TPW];
#pragma unroll
        for (int ti = 0; ti < TPW; ti++) {
            int tile = (HEADS == 4) ? ti : wv;
            unsigned int addr =
                (unsigned int)(size_t)&lh[(head * 4 + tile) * 512] + lane * 8;
            asm volatile("ds_read_b64_tr_b16 %0, %1" : "=v"(b0[ti]) : "v"(addr));
            asm volatile("ds_read_b64_tr_b16 %0, %1 offset:512" : "=v"(b1[ti]) : "v"(addr));
        }
        asm volatile("s_waitcnt lgkmcnt(0)");
        __builtin_amdgcn_sched_barrier(0);
#pragma unroll
        for (int ti = 0; ti < TPW; ti++) {
            f16x8 bfr = __builtin_shufflevector(b0[ti], b1[ti], 0, 1, 2, 3, 4, 5, 6, 7);
            acc[ti] = __builtin_amdgcn_mfma_f32_16x16x32_f16(afr.v, bfr, acc[ti], 0, 0, 0);
        }
    }

    // ---- epilogue: D row=(lane>>4)*4+r (node), col=lane&15 (feat) ----
#pragma unroll
    for (int ti = 0; ti < TPW; ti++) {
        int tile = (HEADS == 4) ? ti : wv;
        int col = head * 64 + tile * 16 + n_;
        float bv = bias[col];
#pragma unroll
        for (int r = 0; r < 4; r++) {
            int nn = n0 + kb * 4 + r;
            if (nn < N) {
                float v = acc[ti][r] + bv;
                if (RELU) v = fmaxf(v, 0.f);
                out[(size_t)nn * F + col] = (TOUT)v;
            }
        }
    }
}

// ---------------- launch ----------------

extern "C" void kernel_launch(void* const* d_in, const int* in_sizes, int n_in,
                              void* d_out, int out_size, void* d_ws, size_t ws_size,
                              hipStream_t stream) {
    const float* x   = (const float*)d_in[0];
    const int*   src = (const int*)d_in[1];
    const int*   dst = (const int*)d_in[2];
    const float* W0  = (const float*)d_in[3];
    const float* al0 = (const float*)d_in[4];
    const float* ar0 = (const float*)d_in[5];
    const float* b0  = (const float*)d_in[6];
    const float* W1  = (const float*)d_in[7];
    const float* al1 = (const float*)d_in[8];
    const float* ar1 = (const float*)d_in[9];
    const float* b1  = (const float*)d_in[10];
    float* out = (float*)d_out;

    const int N = in_sizes[0] / 256;  // 50000
    const int E = in_sizes[1];        // 800000

    char* ws = (char*)d_ws;
    size_t off = 0;
    auto alloc = [&](size_t bytes) -> void* {
        void* p = ws + off;
        off += (bytes + 255) / 256 * 256;
        return p;
    };
    f16* h0        = (f16*)alloc((size_t)N * 256 * 2);
    f16* y         = (f16*)alloc((size_t)N * 256 * 2);
    f16* h1        = (f16*)alloc((size_t)N * 64 * 2);
    float* el0     = (float*)alloc((size_t)N * 4 * 4);
    float* er0     = (float*)alloc((size_t)N * 4 * 4);
    float* m0      = (float*)alloc((size_t)N * 4 * 4);
    float* is0     = (float*)alloc((size_t)N * 4 * 4);
    float* el1     = (float*)alloc((size_t)N * 4);
    float* er1     = (float*)alloc((size_t)N * 4);
    float* m1      = (float*)alloc((size_t)N * 4);
    float* is1     = (float*)alloc((size_t)N * 4);
    int* counts    = (int*)alloc((size_t)N * 4);
    int* indptr    = (int*)alloc((size_t)(N + 1) * 4);
    int* cursor    = (int*)alloc((size_t)N * 4);
    int* csrc      = (int*)alloc((size_t)E * 4);
    int* cdst      = (int*)alloc((size_t)E * 4);
    int* blocksums = (int*)alloc(64 * 4);

    // ---- CSR build (by dst) ----
    hipMemsetAsync(counts, 0, (size_t)N * 4, stream);
    count_dst<<<(E + 255) / 256, 256, 0, stream>>>(dst, counts, E);
    int nb = (N + 1023) / 1024;  // 49
    scan_local<<<nb, 256, 0, stream>>>(counts, indptr, blocksums, N);
    scan_carry<<<1, 64, 0, stream>>>(blocksums, nb);
    scan_add<<<nb, 256, 0, stream>>>(indptr, blocksums, N, E);
    hipMemcpyAsync(cursor, indptr, (size_t)N * 4, hipMemcpyDeviceToDevice, stream);
    fill_csr<<<(E + 255) / 256, 256, 0, stream>>>(dst, src, cursor, csrc, cdst, E);

    int mtiles = (N + 63) / 64;   // 782
    int atiles = (N + 15) / 16;   // 3125

    // ---- layer 0 ----
    gemm_mfma<256, float><<<mtiles, 256, 0, stream>>>(x, W0, h0, N);
    elr_kernel<4><<<(N + 3) / 4, 256, 0, stream>>>(h0, al0, ar0, el0, er0, N);
    ms_kernel<4><<<(N + 3) / 4, 256, 0, stream>>>(el0, er0, indptr, csrc, m0, is0, N);
    agg_mfma<4, true, f16><<<atiles, 256, 0, stream>>>(h0, el0, er0, m0, is0, b0,
                                                       indptr, csrc, cdst, y, N, E);

    // ---- layer 1 ----
    gemm_mfma<64, f16><<<mtiles, 256, 0, stream>>>(y, W1, h1, N);
    elr_kernel<1><<<(N + 15) / 16, 256, 0, stream>>>(h1, al1, ar1, el1, er1, N);
    ms_kernel<1><<<(N + 3) / 4, 256, 0, stream>>>(el1, er1, indptr, csrc, m1, is1, N);
    agg_mfma<1, false, float><<<atiles, 256, 0, stream>>>(h1, el1, er1, m1, is1, b1,
                                                          indptr, csrc, cdst, out, N, E);
}

// Round 6
// 283.449 us; speedup vs baseline: 1.0386x; 1.0386x over previous
//
#include <hip/hip_runtime.h>
#include <math.h>

#define NEG_SLOPE 0.2f

using f16   = _Float16;
using f16x4 = __attribute__((ext_vector_type(4))) _Float16;
using f16x8 = __attribute__((ext_vector_type(8))) _Float16;
using f32x4 = __attribute__((ext_vector_type(4))) float;

// ---------------- CSR build ----------------

__global__ void count_dst(const int* __restrict__ dst, int* __restrict__ counts, int E) {
    int e = blockIdx.x * blockDim.x + threadIdx.x;
    if (e < E) atomicAdd(&counts[dst[e]], 1);
}

__global__ void scan_local(const int* __restrict__ counts, int* __restrict__ indptr,
                           int* __restrict__ blocksums, int n) {
    __shared__ int sdata[256];
    int b = blockIdx.x, t = threadIdx.x;
    int base = b * 1024 + t * 4;
    int v[4];
    int sum = 0;
#pragma unroll
    for (int j = 0; j < 4; j++) {
        int idx = base + j;
        v[j] = (idx < n) ? counts[idx] : 0;
        sum += v[j];
    }
    sdata[t] = sum;
    __syncthreads();
    for (int o = 1; o < 256; o <<= 1) {
        int u = 0;
        if (t >= o) u = sdata[t - o];
        __syncthreads();
        if (t >= o) sdata[t] += u;
        __syncthreads();
    }
    int excl = (t > 0) ? sdata[t - 1] : 0;
    int run = excl;
#pragma unroll
    for (int j = 0; j < 4; j++) {
        int idx = base + j;
        if (idx < n) indptr[idx] = run;
        run += v[j];
    }
    if (t == 255) blocksums[b] = sdata[255];
}

__global__ void scan_carry(int* __restrict__ blocksums, int nb) {
    int t = threadIdx.x;
    int v = (t < nb) ? blocksums[t] : 0;
    int orig = v;
#pragma unroll
    for (int o = 1; o < 64; o <<= 1) {
        int u = __shfl_up(v, o);
        if (t >= o) v += u;
    }
    if (t < nb) blocksums[t] = v - orig;
}

__global__ void scan_add(int* __restrict__ indptr, const int* __restrict__ blocksums,
                         int n, int Etot) {
    int b = blockIdx.x, t = threadIdx.x;
    int base = b * 1024 + t * 4;
    int add = blocksums[b];
#pragma unroll
    for (int j = 0; j < 4; j++) {
        int idx = base + j;
        if (idx < n) indptr[idx] += add;
    }
    if (b == 0 && t == 0) indptr[n] = Etot;
}

__global__ void fill_csr(const int* __restrict__ dst, const int* __restrict__ src,
                         int* __restrict__ cursor, int* __restrict__ csrc, int E) {
    int e = blockIdx.x * blockDim.x + threadIdx.x;
    if (e < E) {
        int p = atomicAdd(&cursor[dst[e]], 1);
        csrc[p] = src[e];
    }
}

// ---------------- f16-MFMA GEMM: C[M][BN] = A[M][256] * B[BN][256]^T, C in f16 ----

template <int BN, typename TA>
__global__ __launch_bounds__(256) void gemm_mfma(const TA* __restrict__ A,
                                                 const float* __restrict__ B,
                                                 f16* __restrict__ C, int M) {
    constexpr int K = 256;
    constexpr int WAVES_N = BN / 64;
    constexpr int WAVES_M = 4 / WAVES_N;
    constexpr int WM = 64 / WAVES_M;
    constexpr int MF = WM / 16;

    __shared__ f16 as[64][40];
    __shared__ f16 bs[BN][40];

    int t = threadIdx.x;
    int wave = t >> 6, lane = t & 63;
    int wn = wave / WAVES_M;
    int wm = wave % WAVES_M;
    int row0 = blockIdx.x * 64;

    int srow = t >> 2;
    int skq = (t & 3) * 8;

    int lrow = lane & 15;
    int ksel = (lane >> 4) * 8;

    f32x4 acc[MF][4] = {};

    for (int k0 = 0; k0 < K; k0 += 32) {
        {
            int gr = row0 + srow;
            gr = gr < M ? gr : M - 1;
            if constexpr (sizeof(TA) == 4) {
                const float4* pa = (const float4*)(A + (size_t)gr * K + k0 + skq);
                float4 u0 = pa[0], u1 = pa[1];
                f16x8 av;
                av[0] = (f16)u0.x; av[1] = (f16)u0.y; av[2] = (f16)u0.z; av[3] = (f16)u0.w;
                av[4] = (f16)u1.x; av[5] = (f16)u1.y; av[6] = (f16)u1.z; av[7] = (f16)u1.w;
                *(f16x8*)&as[srow][skq] = av;
            } else {
                *(f16x8*)&as[srow][skq] = *(const f16x8*)(A + (size_t)gr * K + k0 + skq);
            }
        }
#pragma unroll
        for (int i = 0; i < BN / 64; i++) {
            int n = i * 64 + srow;
            const float4* pb = (const float4*)(B + (size_t)n * K + k0 + skq);
            float4 u0 = pb[0], u1 = pb[1];
            f16x8 bv;
            bv[0] = (f16)u0.x; bv[1] = (f16)u0.y; bv[2] = (f16)u0.z; bv[3] = (f16)u0.w;
            bv[4] = (f16)u1.x; bv[5] = (f16)u1.y; bv[6] = (f16)u1.z; bv[7] = (f16)u1.w;
            *(f16x8*)&bs[n][skq] = bv;
        }
        __syncthreads();

        f16x8 af[MF], bf[4];
#pragma unroll
        for (int i = 0; i < MF; i++)
            af[i] = *(const f16x8*)&as[wm * WM + i * 16 + lrow][ksel];
#pragma unroll
        for (int j = 0; j < 4; j++)
            bf[j] = *(const f16x8*)&bs[wn * 64 + j * 16 + lrow][ksel];
#pragma unroll
        for (int i = 0; i < MF; i++)
#pragma unroll
            for (int j = 0; j < 4; j++)
                acc[i][j] = __builtin_amdgcn_mfma_f32_16x16x32_f16(af[i], bf[j], acc[i][j], 0, 0, 0);
        __syncthreads();
    }

#pragma unroll
    for (int i = 0; i < MF; i++) {
        int r0 = row0 + wm * WM + i * 16 + (lane >> 4) * 4;
#pragma unroll
        for (int j = 0; j < 4; j++) {
            int col = wn * 64 + j * 16 + (lane & 15);
#pragma unroll
            for (int r = 0; r < 4; r++) {
                int gr = r0 + r;
                if (gr < M) C[(size_t)gr * BN + col] = (f16)acc[i][j][r];
            }
        }
    }
}

// ---------------- attention scalars: el/er per node per head ----------------

template <int HEADS>
__global__ __launch_bounds__(256) void elr_kernel(const f16* __restrict__ h,
                                                  const float* __restrict__ al,
                                                  const float* __restrict__ ar,
                                                  float* __restrict__ el,
                                                  float* __restrict__ er, int N) {
    constexpr int F = HEADS * 64;
    constexpr int LPN = HEADS * 16;
    constexpr int NPW = 64 / LPN;
    int t = threadIdx.x;
    int wave = t >> 6, lane = t & 63;
    int node = (blockIdx.x * 4 + wave) * NPW + lane / LPN;
    int fl = lane % LPN;
    int feat = fl * 4;
    int head = feat >> 6;
    if (node >= N) return;
    f16x4 hv = *(const f16x4*)&h[(size_t)node * F + feat];
    float4 av = *(const float4*)&al[feat];
    float4 rv = *(const float4*)&ar[feat];
    float a_ = (float)hv[0] * av.x + (float)hv[1] * av.y + (float)hv[2] * av.z + (float)hv[3] * av.w;
    float b_ = (float)hv[0] * rv.x + (float)hv[1] * rv.y + (float)hv[2] * rv.z + (float)hv[3] * rv.w;
#pragma unroll
    for (int o = 1; o <= 8; o <<= 1) {
        a_ += __shfl_xor(a_, o);
        b_ += __shfl_xor(b_, o);
    }
    if ((lane & 15) == 0) {
        el[node * HEADS + head] = a_;
        er[node * HEADS + head] = b_;
    }
}

// ---------------- per-node softmax + packed alpha precompute ----------------
// wave per node; lane = e*HEADS + h. Pass 1: online max/sum. Pass 2: write
// af_pack[(edge)*H + h] = (dst&15)<<16 | f16(alpha).

template <int HEADS>
__global__ __launch_bounds__(256) void ms_kernel(const float* __restrict__ el,
                                                 const float* __restrict__ er,
                                                 const int* __restrict__ indptr,
                                                 const int* __restrict__ csrc,
                                                 unsigned int* __restrict__ af_pack,
                                                 int N) {
    constexpr int EPC = 64 / HEADS;
    int wv = threadIdx.x >> 6, lane = threadIdx.x & 63;
    int node = blockIdx.x * 4 + wv;
    if (node >= N) return;
    int beg = indptr[node], end = indptr[node + 1], deg = end - beg;
    if (deg == 0) return;
    int h = lane % HEADS;
    int e = lane / HEADS;
    float erh = er[node * HEADS + h];
    float m = -INFINITY, s = 0.f;
    for (int c0 = 0; c0 < deg; c0 += EPC) {
        int i = c0 + e;
        float lg = -INFINITY;
        if (i < deg) {
            int sd = csrc[beg + i];
            lg = el[sd * HEADS + h] + erh;
            lg = lg >= 0.f ? lg : NEG_SLOPE * lg;
        }
        float cm = lg;
#pragma unroll
        for (int o = HEADS; o < 64; o <<= 1) cm = fmaxf(cm, __shfl_xor(cm, o));
        float mnew = fmaxf(m, cm);
        float p = (i < deg) ? __expf(lg - mnew) : 0.f;
#pragma unroll
        for (int o = HEADS; o < 64; o <<= 1) p += __shfl_xor(p, o);
        float r = (m > -INFINITY) ? __expf(m - mnew) : 0.f;
        s = s * r + p;
        m = mnew;
    }
    float invs = 1.f / s;
    unsigned int owner = (unsigned int)(node & 15) << 16;
    for (int c0 = 0; c0 < deg; c0 += EPC) {
        int i = c0 + e;
        if (i < deg) {
            int sd = csrc[beg + i];
            float lg = el[sd * HEADS + h] + erh;
            lg = lg >= 0.f ? lg : NEG_SLOPE * lg;
            float a = __expf(lg - m) * invs;
            f16 a16 = (f16)a;
            af_pack[(size_t)(beg + i) * HEADS + h] =
                owner | (unsigned int)__builtin_bit_cast(unsigned short, a16);
        }
    }
}

// ---------------- MFMA segment aggregation ----------------
// Block = 16 consecutive dst nodes. Per 32-edge K-step:
//  C[16n][D] += A[16n][32e] x H[32e][D], A[n][e] = alpha (owner-masked).
// Staging map: lane l of wave w, iter i -> edge e=l>>1, f0=8(l&1)+16i+16*NITER*w.
// LDS elem addr = (i+NITER*w)*512 + 8*l  (LINEAR per instruction: 0 conflicts),
// identical logical layout [blk][(e>>2)*64+(e&3)*16+(f&15)] as the tr_read needs.
// B-frag via ds_read_b64_tr_b16 (lane l -> H[e=4*(l>>4)+j][d=l&15]);
// K-perm sigma(kb,j): j<4 -> 4*kb+j ; j>=4 -> 16+4*kb+(j-4); A uses same sigma.
// T14: next step's gather issued right after barrier 2, overlaps frag+MFMA.

template <int HEADS, bool RELU, typename TOUT>
__global__ __launch_bounds__(256) void agg_mfma(
        const f16* __restrict__ h, const unsigned int* __restrict__ af_pack,
        const float* __restrict__ bias, const int* __restrict__ indptr,
        const int* __restrict__ csrc, TOUT* __restrict__ out, int N, int E) {
    constexpr int F = HEADS * 64;
    constexpr int TPW = (HEADS == 4) ? 4 : 1;   // 16-feat tiles per wave
    constexpr int NITER = HEADS;                // f16x8 gathers per thread/step

    __shared__ f16 lh[HEADS * 4 * 512];
    __shared__ unsigned int af_s[32 * HEADS];

    int t = threadIdx.x;
    int wv = t >> 6, lane = t & 63;
    int n0 = blockIdx.x * 16;
    int ntop = (n0 + 16 < N) ? n0 + 16 : N;
    int kbeg = indptr[n0], kend = indptr[ntop];
    int head = (HEADS == 4) ? wv : 0;
    int n_ = lane & 15, kb = lane >> 4;
    int e_ = lane >> 1;

    f32x4 acc[TPW];
#pragma unroll
    for (int i = 0; i < TPW; i++) acc[i] = (f32x4){0.f, 0.f, 0.f, 0.f};

    f16x8 rg[NITER];
    unsigned int af_r = 0;

    auto issue = [&](int kb0) {
        int pos = kb0 + e_;
        int posc = pos < E ? pos : E - 1;
        const f16* row = h + (size_t)csrc[posc] * F;
#pragma unroll
        for (int i = 0; i < NITER; i++)
            rg[i] = *(const f16x8*)(row + 8 * (lane & 1) + 16 * i + 16 * NITER * wv);
        int at = kb0 * HEADS + t;
        af_r = (t < 32 * HEADS && at < kend * HEADS) ? af_pack[at] : 0u;
    };

    if (kbeg < kend) issue(kbeg);

    for (int kb0 = kbeg; kb0 < kend; kb0 += 32) {
        __syncthreads();   // prior compute done reading lh/af_s
#pragma unroll
        for (int i = 0; i < NITER; i++)
            *(f16x8*)&lh[(i + NITER * wv) * 512 + lane * 8] = rg[i];
        if (t < 32 * HEADS) af_s[t] = af_r;
        __syncthreads();
        if (kb0 + 32 < kend) issue(kb0 + 32);   // overlaps with compute below

        // A fragment: alpha[sigma(kb,jj)] masked by owner==n_
        union { unsigned int u[4]; f16x8 v; } afr;
#pragma unroll
        for (int jj = 0; jj < 8; jj++) {
            int e = (jj < 4) ? (kb * 4 + jj) : (16 + kb * 4 + (jj - 4));
            unsigned int v = af_s[e * HEADS + head];
            unsigned int ab = ((v >> 16) == (unsigned int)n_) ? (v & 0xffffu) : 0u;
            if (jj & 1) afr.u[jj >> 1] |= ab << 16;
            else        afr.u[jj >> 1] = ab;
        }

        // B fragments via hardware transpose read
        f16x4 b0[TPW], b1[TPW];
#pragma unroll
        for (int ti = 0; ti < TPW; ti++) {
            int tile = (HEADS == 4) ? ti : wv;
            unsigned int addr =
                (unsigned int)(size_t)&lh[(head * 4 + tile) * 512] + lane * 8;
            asm volatile("ds_read_b64_tr_b16 %0, %1" : "=v"(b0[ti]) : "v"(addr));
            asm volatile("ds_read_b64_tr_b16 %0, %1 offset:512" : "=v"(b1[ti]) : "v"(addr));
        }
        asm volatile("s_waitcnt lgkmcnt(0)");
        __builtin_amdgcn_sched_barrier(0);
#pragma unroll
        for (int ti = 0; ti < TPW; ti++) {
            f16x8 bfr = __builtin_shufflevector(b0[ti], b1[ti], 0, 1, 2, 3, 4, 5, 6, 7);
            acc[ti] = __builtin_amdgcn_mfma_f32_16x16x32_f16(afr.v, bfr, acc[ti], 0, 0, 0);
        }
    }

    // epilogue: D row=(lane>>4)*4+r (node), col=lane&15 (feat)
#pragma unroll
    for (int ti = 0; ti < TPW; ti++) {
        int tile = (HEADS == 4) ? ti : wv;
        int col = head * 64 + tile * 16 + n_;
        float bv = bias[col];
#pragma unroll
        for (int r = 0; r < 4; r++) {
            int nn = n0 + kb * 4 + r;
            if (nn < N) {
                float v = acc[ti][r] + bv;
                if (RELU) v = fmaxf(v, 0.f);
                out[(size_t)nn * F + col] = (TOUT)v;
            }
        }
    }
}

// ---------------- launch ----------------

extern "C" void kernel_launch(void* const* d_in, const int* in_sizes, int n_in,
                              void* d_out, int out_size, void* d_ws, size_t ws_size,
                              hipStream_t stream) {
    const float* x   = (const float*)d_in[0];
    const int*   src = (const int*)d_in[1];
    const int*   dst = (const int*)d_in[2];
    const float* W0  = (const float*)d_in[3];
    const float* al0 = (const float*)d_in[4];
    const float* ar0 = (const float*)d_in[5];
    const float* b0  = (const float*)d_in[6];
    const float* W1  = (const float*)d_in[7];
    const float* al1 = (const float*)d_in[8];
    const float* ar1 = (const float*)d_in[9];
    const float* b1  = (const float*)d_in[10];
    float* out = (float*)d_out;

    const int N = in_sizes[0] / 256;  // 50000
    const int E = in_sizes[1];        // 800000

    char* ws = (char*)d_ws;
    size_t off = 0;
    auto alloc = [&](size_t bytes) -> void* {
        void* p = ws + off;
        off += (bytes + 255) / 256 * 256;
        return p;
    };
    f16* h0        = (f16*)alloc((size_t)N * 256 * 2);
    f16* y         = (f16*)alloc((size_t)N * 256 * 2);
    f16* h1        = (f16*)alloc((size_t)N * 64 * 2);
    float* el0     = (float*)alloc((size_t)N * 4 * 4);
    float* er0     = (float*)alloc((size_t)N * 4 * 4);
    float* el1     = (float*)alloc((size_t)N * 4);
    float* er1     = (float*)alloc((size_t)N * 4);
    unsigned int* af0 = (unsigned int*)alloc((size_t)E * 4 * 4);
    unsigned int* af1 = (unsigned int*)alloc((size_t)E * 4);
    int* counts    = (int*)alloc((size_t)N * 4);
    int* indptr    = (int*)alloc((size_t)(N + 1) * 4);
    int* cursor    = (int*)alloc((size_t)N * 4);
    int* csrc      = (int*)alloc((size_t)E * 4);
    int* blocksums = (int*)alloc(64 * 4);

    // ---- CSR build (by dst) ----
    hipMemsetAsync(counts, 0, (size_t)N * 4, stream);
    count_dst<<<(E + 255) / 256, 256, 0, stream>>>(dst, counts, E);
    int nb = (N + 1023) / 1024;  // 49
    scan_local<<<nb, 256, 0, stream>>>(counts, indptr, blocksums, N);
    scan_carry<<<1, 64, 0, stream>>>(blocksums, nb);
    scan_add<<<nb, 256, 0, stream>>>(indptr, blocksums, N, E);
    hipMemcpyAsync(cursor, indptr, (size_t)N * 4, hipMemcpyDeviceToDevice, stream);
    fill_csr<<<(E + 255) / 256, 256, 0, stream>>>(dst, src, cursor, csrc, E);

    int mtiles = (N + 63) / 64;   // 782
    int atiles = (N + 15) / 16;   // 3125

    // ---- layer 0 ----
    gemm_mfma<256, float><<<mtiles, 256, 0, stream>>>(x, W0, h0, N);
    elr_kernel<4><<<(N + 3) / 4, 256, 0, stream>>>(h0, al0, ar0, el0, er0, N);
    ms_kernel<4><<<(N + 3) / 4, 256, 0, stream>>>(el0, er0, indptr, csrc, af0, N);
    agg_mfma<4, true, f16><<<atiles, 256, 0, stream>>>(h0, af0, b0, indptr, csrc, y, N, E);

    // ---- layer 1 ----
    gemm_mfma<64, f16><<<mtiles, 256, 0, stream>>>(y, W1, h1, N);
    elr_kernel<1><<<(N + 15) / 16, 256, 0, stream>>>(h1, al1, ar1, el1, er1, N);
    ms_kernel<1><<<(N + 3) / 4, 256, 0, stream>>>(el1, er1, indptr, csrc, af1, N);
    agg_mfma<1, false, float><<<atiles, 256, 0, stream>>>(h1, af1, b1, indptr, csrc, out, N, E);
}

// Round 7
// 265.726 us; speedup vs baseline: 1.1078x; 1.0667x over previous
//
#include <hip/hip_runtime.h>
#include <math.h>

#define NEG_SLOPE 0.2f

using f16   = _Float16;
using f16x4 = __attribute__((ext_vector_type(4))) _Float16;
using f16x8 = __attribute__((ext_vector_type(8))) _Float16;
using f32x4 = __attribute__((ext_vector_type(4))) float;

// ---------------- CSR build ----------------

__global__ void count_dst(const int* __restrict__ dst, int* __restrict__ counts, int E) {
    int e = blockIdx.x * blockDim.x + threadIdx.x;
    if (e < E) atomicAdd(&counts[dst[e]], 1);
}

__global__ void scan_local(const int* __restrict__ counts, int* __restrict__ indptr,
                           int* __restrict__ blocksums, int n) {
    __shared__ int sdata[256];
    int b = blockIdx.x, t = threadIdx.x;
    int base = b * 1024 + t * 4;
    int v[4];
    int sum = 0;
#pragma unroll
    for (int j = 0; j < 4; j++) {
        int idx = base + j;
        v[j] = (idx < n) ? counts[idx] : 0;
        sum += v[j];
    }
    sdata[t] = sum;
    __syncthreads();
    for (int o = 1; o < 256; o <<= 1) {
        int u = 0;
        if (t >= o) u = sdata[t - o];
        __syncthreads();
        if (t >= o) sdata[t] += u;
        __syncthreads();
    }
    int excl = (t > 0) ? sdata[t - 1] : 0;
    int run = excl;
#pragma unroll
    for (int j = 0; j < 4; j++) {
        int idx = base + j;
        if (idx < n) indptr[idx] = run;
        run += v[j];
    }
    if (t == 255) blocksums[b] = sdata[255];
}

__global__ void scan_carry(int* __restrict__ blocksums, int nb) {
    int t = threadIdx.x;
    int v = (t < nb) ? blocksums[t] : 0;
    int orig = v;
#pragma unroll
    for (int o = 1; o < 64; o <<= 1) {
        int u = __shfl_up(v, o);
        if (t >= o) v += u;
    }
    if (t < nb) blocksums[t] = v - orig;
}

__global__ void scan_add(int* __restrict__ indptr, const int* __restrict__ blocksums,
                         int n, int Etot) {
    int b = blockIdx.x, t = threadIdx.x;
    int base = b * 1024 + t * 4;
    int add = blocksums[b];
#pragma unroll
    for (int j = 0; j < 4; j++) {
        int idx = base + j;
        if (idx < n) indptr[idx] += add;
    }
    if (b == 0 && t == 0) indptr[n] = Etot;
}

__global__ void fill_csr(const int* __restrict__ dst, const int* __restrict__ src,
                         int* __restrict__ cursor, int* __restrict__ csrc, int E) {
    int e = blockIdx.x * blockDim.x + threadIdx.x;
    if (e < E) {
        int p = atomicAdd(&cursor[dst[e]], 1);
        csrc[p] = src[e];
    }
}

// ---------------- f16-MFMA GEMM: C[M][BN] = A[M][256] * B[BN][256]^T, C in f16 ----

template <int BN, typename TA>
__global__ __launch_bounds__(256) void gemm_mfma(const TA* __restrict__ A,
                                                 const float* __restrict__ B,
                                                 f16* __restrict__ C, int M) {
    constexpr int K = 256;
    constexpr int WAVES_N = BN / 64;
    constexpr int WAVES_M = 4 / WAVES_N;
    constexpr int WM = 64 / WAVES_M;
    constexpr int MF = WM / 16;

    __shared__ f16 as[64][40];
    __shared__ f16 bs[BN][40];

    int t = threadIdx.x;
    int wave = t >> 6, lane = t & 63;
    int wn = wave / WAVES_M;
    int wm = wave % WAVES_M;
    int row0 = blockIdx.x * 64;

    int srow = t >> 2;
    int skq = (t & 3) * 8;

    int lrow = lane & 15;
    int ksel = (lane >> 4) * 8;

    f32x4 acc[MF][4] = {};

    for (int k0 = 0; k0 < K; k0 += 32) {
        {
            int gr = row0 + srow;
            gr = gr < M ? gr : M - 1;
            if constexpr (sizeof(TA) == 4) {
                const float4* pa = (const float4*)(A + (size_t)gr * K + k0 + skq);
                float4 u0 = pa[0], u1 = pa[1];
                f16x8 av;
                av[0] = (f16)u0.x; av[1] = (f16)u0.y; av[2] = (f16)u0.z; av[3] = (f16)u0.w;
                av[4] = (f16)u1.x; av[5] = (f16)u1.y; av[6] = (f16)u1.z; av[7] = (f16)u1.w;
                *(f16x8*)&as[srow][skq] = av;
            } else {
                *(f16x8*)&as[srow][skq] = *(const f16x8*)(A + (size_t)gr * K + k0 + skq);
            }
        }
#pragma unroll
        for (int i = 0; i < BN / 64; i++) {
            int n = i * 64 + srow;
            const float4* pb = (const float4*)(B + (size_t)n * K + k0 + skq);
            float4 u0 = pb[0], u1 = pb[1];
            f16x8 bv;
            bv[0] = (f16)u0.x; bv[1] = (f16)u0.y; bv[2] = (f16)u0.z; bv[3] = (f16)u0.w;
            bv[4] = (f16)u1.x; bv[5] = (f16)u1.y; bv[6] = (f16)u1.z; bv[7] = (f16)u1.w;
            *(f16x8*)&bs[n][skq] = bv;
        }
        __syncthreads();

        f16x8 af[MF], bf[4];
#pragma unroll
        for (int i = 0; i < MF; i++)
            af[i] = *(const f16x8*)&as[wm * WM + i * 16 + lrow][ksel];
#pragma unroll
        for (int j = 0; j < 4; j++)
            bf[j] = *(const f16x8*)&bs[wn * 64 + j * 16 + lrow][ksel];
#pragma unroll
        for (int i = 0; i < MF; i++)
#pragma unroll
            for (int j = 0; j < 4; j++)
                acc[i][j] = __builtin_amdgcn_mfma_f32_16x16x32_f16(af[i], bf[j], acc[i][j], 0, 0, 0);
        __syncthreads();
    }

#pragma unroll
    for (int i = 0; i < MF; i++) {
        int r0 = row0 + wm * WM + i * 16 + (lane >> 4) * 4;
#pragma unroll
        for (int j = 0; j < 4; j++) {
            int col = wn * 64 + j * 16 + (lane & 15);
#pragma unroll
            for (int r = 0; r < 4; r++) {
                int gr = r0 + r;
                if (gr < M) C[(size_t)gr * BN + col] = (f16)acc[i][j][r];
            }
        }
    }
}

// ---------------- attention scalars: el/er per node per head ----------------

template <int HEADS>
__global__ __launch_bounds__(256) void elr_kernel(const f16* __restrict__ h,
                                                  const float* __restrict__ al,
                                                  const float* __restrict__ ar,
                                                  float* __restrict__ el,
                                                  float* __restrict__ er, int N) {
    constexpr int F = HEADS * 64;
    constexpr int LPN = HEADS * 16;
    constexpr int NPW = 64 / LPN;
    int t = threadIdx.x;
    int wave = t >> 6, lane = t & 63;
    int node = (blockIdx.x * 4 + wave) * NPW + lane / LPN;
    int fl = lane % LPN;
    int feat = fl * 4;
    int head = feat >> 6;
    if (node >= N) return;
    f16x4 hv = *(const f16x4*)&h[(size_t)node * F + feat];
    float4 av = *(const float4*)&al[feat];
    float4 rv = *(const float4*)&ar[feat];
    float a_ = (float)hv[0] * av.x + (float)hv[1] * av.y + (float)hv[2] * av.z + (float)hv[3] * av.w;
    float b_ = (float)hv[0] * rv.x + (float)hv[1] * rv.y + (float)hv[2] * rv.z + (float)hv[3] * rv.w;
#pragma unroll
    for (int o = 1; o <= 8; o <<= 1) {
        a_ += __shfl_xor(a_, o);
        b_ += __shfl_xor(b_, o);
    }
    if ((lane & 15) == 0) {
        el[node * HEADS + head] = a_;
        er[node * HEADS + head] = b_;
    }
}

// ---------------- fused MFMA segment aggregation (softmax inline) ----------------
// Block = 16 consecutive dst nodes. Per 32-edge K-step:
//  C[16n][D] += A[16n][32e] x H[32e][D], A[n][e] = w_e (owner-masked),
//  w_e = exp(leaky(el[src]+er[dst]) - CSH)  [unnormalized; softmax is
//  scale-invariant per dst]. Denominator s[n] = extra MFMA with B = ones
//  column 0 (constant per lane, no LDS). Epilogue: out = acc/s + bias.
// Staging map: lane l of wave w, iter i -> LDS elem addr (i+NITER*w)*512+8l
//  (linear per instruction: 0 write conflicts); logical layout
//  [blk][(e>>2)*64+(e&3)*16+(f&15)] matches ds_read_b64_tr_b16.
// K-perm sigma(kb,j): j<4 -> 4*kb+j ; j>=4 -> 16+4*kb+(j-4); A uses same sigma.
// 2-deep register prefetch: rgA/rgB (+elA/elB), single LDS buffer (the two
// barriers make reuse safe); buffer refilled right after its consuming
// barrier, next use one full step later.

template <int HEADS, bool RELU, typename TOUT>
__global__ __launch_bounds__(256) void agg_mfma(
        const f16* __restrict__ h, const float* __restrict__ el,
        const float* __restrict__ er, const float* __restrict__ bias,
        const int* __restrict__ indptr, const int* __restrict__ csrc,
        TOUT* __restrict__ out, int N, int E) {
    constexpr int F = HEADS * 64;
    constexpr int TPW = (HEADS == 4) ? 4 : 1;   // 16-feat tiles per wave
    constexpr int NITER = HEADS;                // f16x8 gathers per thread/step
    constexpr float CSH = 5.0f;                 // global exp shift (w <= ~e^2)

    __shared__ f16 lh[HEADS * 4 * 512];
    __shared__ unsigned int af_s[32 * HEADS];
    __shared__ float er_s[16 * HEADS];
    __shared__ int iptr_s[17];

    int t = threadIdx.x;
    int wv = t >> 6, lane = t & 63;
    int n0 = blockIdx.x * 16;
    int head = (HEADS == 4) ? wv : 0;
    int n_ = lane & 15, kb = lane >> 4;
    int e_ = lane >> 1;

    if (t < 17) {
        int nn = n0 + t;
        iptr_s[t] = indptr[nn < N ? nn : N];
    }
    if (t < 16 * HEADS) {
        int nn = n0 + t / HEADS;
        er_s[t] = (nn < N) ? er[nn * HEADS + (t % HEADS)] : 0.f;
    }
    __syncthreads();
    int kbeg = iptr_s[0], kend = iptr_s[16];

    f32x4 acc[TPW];
#pragma unroll
    for (int i = 0; i < TPW; i++) acc[i] = (f32x4){0.f, 0.f, 0.f, 0.f};
    f32x4 acc_s = {0.f, 0.f, 0.f, 0.f};

    // constant s-MFMA B fragment: ones in feature-col 0
    f16x8 bones;
#pragma unroll
    for (int i = 0; i < 8; i++) bones[i] = (f16)((n_ == 0) ? 1.f : 0.f);

    f16x8 rgA[NITER], rgB[NITER];
    float4 elA = {0, 0, 0, 0}, elB = {0, 0, 0, 0};

    auto issue = [&](int kb0, f16x8 (&rg)[NITER], float4& el4) {
        int pos = kb0 + e_;
        int posc = pos < E ? pos : E - 1;
        const f16* row = h + (size_t)csrc[posc] * F;
#pragma unroll
        for (int i = 0; i < NITER; i++)
            rg[i] = *(const f16x8*)(row + 8 * (lane & 1) + 16 * i + 16 * NITER * wv);
        if (t < 32) {
            int p2 = kb0 + t;
            int p2c = p2 < E ? p2 : E - 1;
            if constexpr (HEADS == 4)
                el4 = *(const float4*)&el[(size_t)csrc[p2c] * 4];
            else
                el4.x = el[csrc[p2c]];
        }
    };

    auto dostep = [&](int kb0, f16x8 (&rg)[NITER], float4& el4) {
        __syncthreads();   // prior compute done reading lh/af_s
#pragma unroll
        for (int i = 0; i < NITER; i++)
            *(f16x8*)&lh[(i + NITER * wv) * 512 + lane * 8] = rg[i];
        if (t < 32) {
            int pos = kb0 + t;
            unsigned int owner = 0;
#pragma unroll
            for (int i = 1; i < 16; i++) owner += (pos >= iptr_s[i]) ? 1u : 0u;
            unsigned int hi = owner << 16;
            bool ok = pos < kend;
            if constexpr (HEADS == 4) {
                float4 rr = *(const float4*)&er_s[owner * 4];
                float l0 = el4.x + rr.x, l1 = el4.y + rr.y;
                float l2 = el4.z + rr.z, l3 = el4.w + rr.w;
                l0 = l0 >= 0.f ? l0 : NEG_SLOPE * l0;
                l1 = l1 >= 0.f ? l1 : NEG_SLOPE * l1;
                l2 = l2 >= 0.f ? l2 : NEG_SLOPE * l2;
                l3 = l3 >= 0.f ? l3 : NEG_SLOPE * l3;
                uint4 pk;
                pk.x = ok ? (hi | (unsigned int)__builtin_bit_cast(unsigned short, (f16)__expf(l0 - CSH))) : 0u;
                pk.y = ok ? (hi | (unsigned int)__builtin_bit_cast(unsigned short, (f16)__expf(l1 - CSH))) : 0u;
                pk.z = ok ? (hi | (unsigned int)__builtin_bit_cast(unsigned short, (f16)__expf(l2 - CSH))) : 0u;
                pk.w = ok ? (hi | (unsigned int)__builtin_bit_cast(unsigned short, (f16)__expf(l3 - CSH))) : 0u;
                *(uint4*)&af_s[t * 4] = pk;
            } else {
                float l0 = el4.x + er_s[owner];
                l0 = l0 >= 0.f ? l0 : NEG_SLOPE * l0;
                af_s[t] = ok ? (hi | (unsigned int)__builtin_bit_cast(unsigned short, (f16)__expf(l0 - CSH))) : 0u;
            }
        }
        __syncthreads();
        if (kb0 + 64 < kend) issue(kb0 + 64, rg, el4);   // refill, used next round

        // A fragment: w[sigma(kb,jj)] masked by owner==n_
        union { unsigned int u[4]; f16x8 v; } afr;
#pragma unroll
        for (int jj = 0; jj < 8; jj++) {
            int e = (jj < 4) ? (kb * 4 + jj) : (16 + kb * 4 + (jj - 4));
            unsigned int v = af_s[e * HEADS + head];
            unsigned int ab = ((v >> 16) == (unsigned int)n_) ? (v & 0xffffu) : 0u;
            if (jj & 1) afr.u[jj >> 1] |= ab << 16;
            else        afr.u[jj >> 1] = ab;
        }

        // B fragments via hardware transpose read
        f16x4 b0[TPW], b1[TPW];
#pragma unroll
        for (int ti = 0; ti < TPW; ti++) {
            int tile = (HEADS == 4) ? ti : wv;
            unsigned int addr =
                (unsigned int)(size_t)&lh[(head * 4 + tile) * 512] + lane * 8;
            asm volatile("ds_read_b64_tr_b16 %0, %1" : "=v"(b0[ti]) : "v"(addr));
            asm volatile("ds_read_b64_tr_b16 %0, %1 offset:512" : "=v"(b1[ti]) : "v"(addr));
        }
        asm volatile("s_waitcnt lgkmcnt(0)");
        __builtin_amdgcn_sched_barrier(0);
#pragma unroll
        for (int ti = 0; ti < TPW; ti++) {
            f16x8 bfr = __builtin_shufflevector(b0[ti], b1[ti], 0, 1, 2, 3, 4, 5, 6, 7);
            acc[ti] = __builtin_amdgcn_mfma_f32_16x16x32_f16(afr.v, bfr, acc[ti], 0, 0, 0);
        }
        acc_s = __builtin_amdgcn_mfma_f32_16x16x32_f16(afr.v, bones, acc_s, 0, 0, 0);
    };

    if (kbeg < kend) issue(kbeg, rgA, elA);
    if (kbeg + 32 < kend) issue(kbeg + 32, rgB, elB);

    for (int k = kbeg; k < kend; k += 64) {
        dostep(k, rgA, elA);
        if (k + 32 < kend) dostep(k + 32, rgB, elB);
    }

    // denominator broadcast: s for row group kb sits in lane kb*16 (n_==0)
    float sv[4];
#pragma unroll
    for (int r = 0; r < 4; r++) sv[r] = __shfl(acc_s[r], lane & 48);

    // epilogue: D row=(lane>>4)*4+r (node), col=lane&15 (feat)
#pragma unroll
    for (int ti = 0; ti < TPW; ti++) {
        int tile = (HEADS == 4) ? ti : wv;
        int col = head * 64 + tile * 16 + n_;
        float bv = bias[col];
#pragma unroll
        for (int r = 0; r < 4; r++) {
            int nn = n0 + kb * 4 + r;
            if (nn < N) {
                float inv = sv[r] > 0.f ? 1.f / sv[r] : 0.f;
                float v = acc[ti][r] * inv + bv;
                if (RELU) v = fmaxf(v, 0.f);
                out[(size_t)nn * F + col] = (TOUT)v;
            }
        }
    }
}

// ---------------- launch ----------------

extern "C" void kernel_launch(void* const* d_in, const int* in_sizes, int n_in,
                              void* d_out, int out_size, void* d_ws, size_t ws_size,
                              hipStream_t stream) {
    const float* x   = (const float*)d_in[0];
    const int*   src = (const int*)d_in[1];
    const int*   dst = (const int*)d_in[2];
    const float* W0  = (const float*)d_in[3];
    const float* al0 = (const float*)d_in[4];
    const float* ar0 = (const float*)d_in[5];
    const float* b0  = (const float*)d_in[6];
    const float* W1  = (const float*)d_in[7];
    const float* al1 = (const float*)d_in[8];
    const float* ar1 = (const float*)d_in[9];
    const float* b1  = (const float*)d_in[10];
    float* out = (float*)d_out;

    const int N = in_sizes[0] / 256;  // 50000
    const int E = in_sizes[1];        // 800000

    char* ws = (char*)d_ws;
    size_t off = 0;
    auto alloc = [&](size_t bytes) -> void* {
        void* p = ws + off;
        off += (bytes + 255) / 256 * 256;
        return p;
    };
    f16* h0        = (f16*)alloc((size_t)N * 256 * 2);
    f16* y         = (f16*)alloc((size_t)N * 256 * 2);
    f16* h1        = (f16*)alloc((size_t)N * 64 * 2);
    float* el0     = (float*)alloc((size_t)N * 4 * 4);
    float* er0     = (float*)alloc((size_t)N * 4 * 4);
    float* el1     = (float*)alloc((size_t)N * 4);
    float* er1     = (float*)alloc((size_t)N * 4);
    int* counts    = (int*)alloc((size_t)N * 4);
    int* indptr    = (int*)alloc((size_t)(N + 1) * 4);
    int* cursor    = (int*)alloc((size_t)N * 4);
    int* csrc      = (int*)alloc((size_t)E * 4);
    int* blocksums = (int*)alloc(64 * 4);

    // ---- CSR build (by dst) ----
    hipMemsetAsync(counts, 0, (size_t)N * 4, stream);
    count_dst<<<(E + 255) / 256, 256, 0, stream>>>(dst, counts, E);
    int nb = (N + 1023) / 1024;  // 49
    scan_local<<<nb, 256, 0, stream>>>(counts, indptr, blocksums, N);
    scan_carry<<<1, 64, 0, stream>>>(blocksums, nb);
    scan_add<<<nb, 256, 0, stream>>>(indptr, blocksums, N, E);
    hipMemcpyAsync(cursor, indptr, (size_t)N * 4, hipMemcpyDeviceToDevice, stream);
    fill_csr<<<(E + 255) / 256, 256, 0, stream>>>(dst, src, cursor, csrc, E);

    int mtiles = (N + 63) / 64;   // 782
    int atiles = (N + 15) / 16;   // 3125

    // ---- layer 0 ----
    gemm_mfma<256, float><<<mtiles, 256, 0, stream>>>(x, W0, h0, N);
    elr_kernel<4><<<(N + 3) / 4, 256, 0, stream>>>(h0, al0, ar0, el0, er0, N);
    agg_mfma<4, true, f16><<<atiles, 256, 0, stream>>>(h0, el0, er0, b0, indptr, csrc, y, N, E);

    // ---- layer 1 ----
    gemm_mfma<64, f16><<<mtiles, 256, 0, stream>>>(y, W1, h1, N);
    elr_kernel<1><<<(N + 15) / 16, 256, 0, stream>>>(h1, al1, ar1, el1, er1, N);
    agg_mfma<1, false, float><<<atiles, 256, 0, stream>>>(h1, el1, er1, b1, indptr, csrc, out, N, E);
}